// Round 6
// baseline (47.762 us; speedup 1.0000x reference)
//
#include <hip/hip_runtime.h>

// IdentityConvolution: out[b,co,h,w] = sum_c x_real[b,c,h,w]
// (harness compares real part only: out_size = 8*64*256*256 fp32 = 128 MiB)
//
// History:
//  R2 fused (1 thr/float4-group, 64 strided stores): 44.45 us, 4.4 TB/s eff.
//  R4 nt stores: 47.9 us, FETCH unchanged -> reverted.
//  R5 4-way channel split, occ 18%->46%: 46.6 us -> occupancy NOT the limit.
//  Diagnosis: fused write pattern = 64 x 256KiB-strided streams of 256B
//  chunks; fillBufferAligned shows 7 TB/s on contiguous writes. -> R6:
//  split reduce (128MiB read -> 2MB ws) + broadcast (contiguous 128MiB
//  write stream, reads 2MB from L2/L3).

#define CHANNELS 64
#define HW (256 * 256)
#define HW4 (HW / 4)        // 16384 float4 groups per plane
#define OUT_SHIFT 20        // log2(CHANNELS * HW4) = log2(2^20)

typedef float f4 __attribute__((ext_vector_type(4)));

// ---- K1: channel reduce. r[b*HW4 + p4] = sum_c xr[b,c,p4] ----
__global__ __launch_bounds__(256)
void channel_sum_kernel(const f4* __restrict__ xr,
                        f4* __restrict__ r,
                        int total) {
    int gid = blockIdx.x * blockDim.x + threadIdx.x;
    if (gid >= total) return;

    int b  = gid >> 14;          // / HW4
    int p4 = gid & (HW4 - 1);

    const f4* base = xr + (size_t)b * CHANNELS * HW4 + p4;
    f4 s = (f4)(0.f);
    #pragma unroll 16
    for (int c = 0; c < CHANNELS; ++c)
        s += base[(size_t)c * HW4];

    r[gid] = s;
}

// ---- K2: broadcast. out[i] = r[b(i)*HW4 + p4(i)], contiguous stores ----
__global__ __launch_bounds__(256)
void broadcast_kernel(const f4* __restrict__ r,
                      f4* __restrict__ out,
                      int total_out) {
    int stride = gridDim.x * blockDim.x;
    for (int i = blockIdx.x * blockDim.x + threadIdx.x; i < total_out; i += stride) {
        int b  = i >> OUT_SHIFT;         // / (CHANNELS*HW4)
        int p4 = i & (HW4 - 1);
        out[i] = r[(b << 14) + p4];
    }
}

// ---- Fallback: fused (R2 structure), used if ws too small ----
__global__ __launch_bounds__(256)
void identity_conv_fused_kernel(const f4* __restrict__ xr,
                                f4* __restrict__ out,
                                int total) {
    int gid = blockIdx.x * blockDim.x + threadIdx.x;
    if (gid >= total) return;

    int b  = gid >> 14;
    int p4 = gid & (HW4 - 1);

    const f4* xr_b = xr + (size_t)b * CHANNELS * HW4 + p4;
    f4 s = (f4)(0.f);
    #pragma unroll 16
    for (int c = 0; c < CHANNELS; ++c)
        s += xr_b[(size_t)c * HW4];

    f4* ob = out + (size_t)b * CHANNELS * HW4 + p4;
    #pragma unroll 16
    for (int co = 0; co < CHANNELS; ++co)
        ob[(size_t)co * HW4] = s;
}

// ---- Fallback: interleaved complex64 (if out_size is the full complex) ----
__global__ __launch_bounds__(256)
void identity_conv_cplx_kernel(const f4* __restrict__ xr,
                               const f4* __restrict__ xi,
                               f4* __restrict__ out,
                               int total) {
    int gid = blockIdx.x * blockDim.x + threadIdx.x;
    if (gid >= total) return;

    int b  = gid >> 14;
    int p4 = gid & (HW4 - 1);

    const f4* xr_b = xr + (size_t)b * CHANNELS * HW4 + p4;
    const f4* xi_b = xi + (size_t)b * CHANNELS * HW4 + p4;

    f4 r  = (f4)(0.f);
    f4 im = (f4)(0.f);
    #pragma unroll 8
    for (int c = 0; c < CHANNELS; ++c) {
        r  += xr_b[(size_t)c * HW4];
        im += xi_b[(size_t)c * HW4];
    }

    f4 lo = (f4){r.x, im.x, r.y, im.y};
    f4 hi = (f4){r.z, im.z, r.w, im.w};

    f4* ob = out + (size_t)b * CHANNELS * (HW / 2) + (size_t)p4 * 2;
    #pragma unroll 4
    for (int co = 0; co < CHANNELS; ++co) {
        ob[0] = lo;
        ob[1] = hi;
        ob += HW / 2;
    }
}

extern "C" void kernel_launch(void* const* d_in, const int* in_sizes, int n_in,
                              void* d_out, int out_size, void* d_ws, size_t ws_size,
                              hipStream_t stream) {
    const f4* xr = (const f4*)d_in[0];
    const f4* xi = (const f4*)d_in[1];
    f4* out = (f4*)d_out;

    int n = in_sizes[0];                 // B * C * HW
    int B = n / (CHANNELS * HW);         // 8
    int total_r = B * HW4;               // 131,072 r-groups (2 MB)

    const int block = 256;

    if (out_size >= 2 * n) {
        int grid = (total_r + block - 1) / block;
        identity_conv_cplx_kernel<<<grid, block, 0, stream>>>(xr, xi, out, total_r);
        return;
    }

    size_t ws_needed = (size_t)total_r * sizeof(f4);   // 2 MiB
    if (ws_size >= ws_needed) {
        f4* r = (f4*)d_ws;
        int grid1 = (total_r + block - 1) / block;           // 512 blocks
        channel_sum_kernel<<<grid1, block, 0, stream>>>(xr, r, total_r);

        int total_out = out_size / 4;                        // 8,388,608 f4
        int grid2 = 2048;                                    // 8 blocks/CU
        broadcast_kernel<<<grid2, block, 0, stream>>>(r, out, total_out);
    } else {
        int grid = (total_r + block - 1) / block;
        identity_conv_fused_kernel<<<grid, block, 0, stream>>>(xr, out, total_r);
    }
}

// Round 7
// 44.213 us; speedup vs baseline: 1.0803x; 1.0803x over previous
//
#include <hip/hip_runtime.h>

// IdentityConvolution: out[b,co,h,w] = sum_c x_real[b,c,h,w]
// (harness compares real part only: out_size = 8*64*256*256 fp32 = 128 MiB)
//
// FINAL (revert to R2 structure — best measured 44.45 us):
//  R2 fused, 1 thread per float4 pixel-group, 64 strided plane stores: 44.45 us
//  R4 nontemporal stores:            47.9 us, FETCH unchanged -> reverted
//  R5 4-way channel split (occ 46%): 46.6 us -> occupancy not the limit
//  R6 reduce(2MB ws)+broadcast:      47.8 us -> contiguous writes no better
// Ceiling analysis: logical traffic = 134MB read + 134MB write = 268MB.
// 268MB / 44.45us = 6.04 TB/s = 96% of the 6.29 TB/s measured float4-copy
// (mixed-stream) ceiling. This is the roofline; all variants confirm it.

#define CHANNELS 64
#define HW (256 * 256)
#define HW4 (HW / 4)   // 16384 float4 groups per plane

typedef float f4 __attribute__((ext_vector_type(4)));

// ---- Path A: real part only. out[b,co,p] = sum_c xr[b,c,p] ----
__global__ __launch_bounds__(256)
void identity_conv_real_kernel(const f4* __restrict__ xr,
                               f4* __restrict__ out,
                               int total) {
    int gid = blockIdx.x * blockDim.x + threadIdx.x;
    if (gid >= total) return;

    int b  = gid >> 14;          // / HW4
    int p4 = gid & (HW4 - 1);

    const f4* xr_b = xr + (size_t)b * CHANNELS * HW4 + p4;

    f4 r = (f4)(0.f);
    #pragma unroll 8
    for (int c = 0; c < CHANNELS; ++c)
        r += xr_b[(size_t)c * HW4];

    f4* ob = out + (size_t)b * CHANNELS * HW4 + p4;
    #pragma unroll 8
    for (int co = 0; co < CHANNELS; ++co)
        ob[(size_t)co * HW4] = r;
}

// ---- Path B (fallback): interleaved complex64 pairs ----
__global__ __launch_bounds__(256)
void identity_conv_cplx_kernel(const f4* __restrict__ xr,
                               const f4* __restrict__ xi,
                               f4* __restrict__ out,
                               int total) {
    int gid = blockIdx.x * blockDim.x + threadIdx.x;
    if (gid >= total) return;

    int b  = gid >> 14;
    int p4 = gid & (HW4 - 1);

    const f4* xr_b = xr + (size_t)b * CHANNELS * HW4 + p4;
    const f4* xi_b = xi + (size_t)b * CHANNELS * HW4 + p4;

    f4 r  = (f4)(0.f);
    f4 im = (f4)(0.f);
    #pragma unroll 8
    for (int c = 0; c < CHANNELS; ++c) {
        r  += xr_b[(size_t)c * HW4];
        im += xi_b[(size_t)c * HW4];
    }

    f4 lo = (f4){r.x, im.x, r.y, im.y};
    f4 hi = (f4){r.z, im.z, r.w, im.w};

    f4* ob = out + (size_t)b * CHANNELS * (HW / 2) + (size_t)p4 * 2;
    #pragma unroll 4
    for (int co = 0; co < CHANNELS; ++co) {
        ob[0] = lo;
        ob[1] = hi;
        ob += HW / 2;
    }
}

extern "C" void kernel_launch(void* const* d_in, const int* in_sizes, int n_in,
                              void* d_out, int out_size, void* d_ws, size_t ws_size,
                              hipStream_t stream) {
    const f4* xr = (const f4*)d_in[0];
    const f4* xi = (const f4*)d_in[1];
    f4* out = (f4*)d_out;

    int n = in_sizes[0];                 // B * C * HW
    int B = n / (CHANNELS * HW);         // 8
    int total = B * HW4;                 // 131,072 float4 groups

    const int block = 256;
    int grid = (total + block - 1) / block;

    if (out_size >= 2 * n) {
        identity_conv_cplx_kernel<<<grid, block, 0, stream>>>(xr, xi, out, total);
    } else {
        identity_conv_real_kernel<<<grid, block, 0, stream>>>(xr, out, total);
    }
}